// Round 6
// baseline (102.090 us; speedup 1.0000x reference)
//
#include <hip/hip_runtime.h>

// out[b][t][w] (f32x4) = x[b][(t + w - 15) mod T] (f32x4)
// B=128, T=16384, F=4, wow=16.
//
// Wave-autonomous sweep: 8192 fully-resident waves, 16 iterations, no LDS,
// no barriers. Per iteration a wave emits one 4 KB output chunk (16 t-rows):
// lanes 0..30 load the 31 needed x rows (1 dwordx4 load/wave, cache-hit),
// __shfl distributes them, 4 coalesced NT dwordx4 stores/lane. Device-wide,
// iteration m writes one contiguous 32 MB span (DRAM-row-friendly sweep).

typedef float f32x4 __attribute__((ext_vector_type(4)));

__global__ __launch_bounds__(256, 8) void ring_pad_kernel(
    const f32x4* __restrict__ x, f32x4* __restrict__ out) {
    constexpr int T    = 16384;
    constexpr int ITER = 16;
    constexpr int NWAVE = 8192;

    int lane = threadIdx.x & 63;
    int g = (blockIdx.x * blockDim.x + threadIdx.x) >> 6;  // global wave id

    int w  = lane & 15;              // window slot
    int tl = (lane >> 4) & 3;        // row-within-quad
    int j  = lane < 31 ? lane : 30;  // source-row slot held by this lane

    #pragma unroll 2
    for (int m = 0; m < ITER; ++m) {
        int c  = m * NWAVE + g;      // 16-row chunk id (device-wide sweep)
        int b  = c >> 10;            // batch
        int R0 = (c & 1023) << 4;    // first output t-row of chunk

        // lane j holds x[b, (R0 - 15 + j) mod T]
        f32x4 r = x[((size_t)b << 14) + ((R0 - 15 + j) & (T - 1))];

        f32x4* ob = out + ((size_t)c << 8);
        #pragma unroll
        for (int s = 0; s < 4; ++s) {
            int src = s * 4 + tl + w;          // 0..30
            f32x4 v;
            v[0] = __shfl(r[0], src, 64);
            v[1] = __shfl(r[1], src, 64);
            v[2] = __shfl(r[2], src, 64);
            v[3] = __shfl(r[3], src, 64);
            __builtin_nontemporal_store(v, &ob[s * 64 + lane]);
        }
    }
}

extern "C" void kernel_launch(void* const* d_in, const int* in_sizes, int n_in,
                              void* d_out, int out_size, void* d_ws, size_t ws_size,
                              hipStream_t stream) {
    const f32x4* x = (const f32x4*)d_in[0];   // (128, 16384, 4) fp32
    f32x4* out = (f32x4*)d_out;               // (128, 16384, 64) fp32

    ring_pad_kernel<<<2048, 256, 0, stream>>>(x, out);
}